// Round 1
// baseline (309.754 us; speedup 1.0000x reference)
//
#include <hip/hip_runtime.h>
#include <math.h>

// Detector loss: N=65536 samples, G=7 (49 cells), A=3 anchors, C=2 classes.
// bbox_ : (N,15,7,7) predictions, channel 5a+0 = objectness(a), 5a+1..5a+4 = x,y,w,h
// bbox  : (N, 5,7,7) GT,          channel 0 = prob map,        1..4       = x,y,w,h
// cls_  : (N,2) logits; cls : (N,) labels in {1,2}
// out   : scalar fp32

static constexpr int GG_ = 49;

__global__ void zero_kernel(float* out) { if (threadIdx.x == 0) out[0] = 0.0f; }

__global__ __launch_bounds__(256) void loss_kernel(
    const float* __restrict__ pr_all,     // bbox_
    const float* __restrict__ cls_logits, // cls_
    const float* __restrict__ gt_all,     // bbox
    const int*   __restrict__ cls_lbl,    // cls
    float* __restrict__ out, int N)
{
    const int lane   = threadIdx.x & 63;
    const int wid    = blockIdx.x * (blockDim.x >> 6) + (threadIdx.x >> 6);
    const int nwaves = gridDim.x * (blockDim.x >> 6);
    const float invG   = 1.0f / 7.0f;
    const float invN   = 1.0f / (float)N;
    const float invN49 = 1.0f / ((float)N * 49.0f);

    float acc = 0.0f;

    for (int n = wid; n < N; n += nwaves) {
        const float* gt = gt_all + (size_t)n * (5  * GG_);
        const float* pr = pr_all + (size_t)n * (15 * GG_);

        // ---- 1) GT prob map + argmax (min-index tie-break) ----
        float t = -1.0f;                    // sentinel loses to any prob (>=0.01)
        if (lane < GG_) t = gt[lane];

        float v = t; int idx = lane;
        #pragma unroll
        for (int off = 32; off; off >>= 1) {
            float v2 = __shfl_xor(v, off);
            int   i2 = __shfl_xor(idx, off);
            if (v2 > v || (v2 == v && i2 < idx)) { v = v2; idx = i2; }
        }
        const int m  = idx;                 // wave-uniform
        const int mi = m / 7, mj = m - mi * 7;
        const float jf = (float)mj, if_ = (float)mi;

        // ---- 2) predicted objectness maps (channels 0,5,10) ----
        float p0 = 0.5f, p1 = 0.5f, p2 = 0.5f;
        if (lane < GG_) {
            p0 = pr[lane];
            p1 = pr[5  * GG_ + lane];
            p2 = pr[10 * GG_ + lane];
        }

        // ---- 3) scattered gathers at cell m: GT ch1..4 (lanes 1-4),
        //          pred coords ch {5a+1..5a+4} (lanes 5-16) ----
        float cellv = 0.0f;
        if (lane >= 1 && lane <= 4) {
            cellv = gt[lane * GG_ + m];
        } else if (lane >= 5 && lane < 17) {
            int k = lane - 5;
            int a = k >> 2, c = k & 3;
            cellv = pr[(5 * a + 1 + c) * GG_ + m];
        }

        const float g1 = __shfl(cellv, 1);  // GT x
        const float g2 = __shfl(cellv, 2);  // GT y
        const float g3 = __shfl(cellv, 3);  // GT w
        const float g4 = __shfl(cellv, 4);  // GT h

        // target box (replicate reference ordering)
        const float tx  = (g1 + jf) * invG;
        const float ty  = (g2 + if_) * invG;
        const float tx1 = tx - g3 * 0.5f, tx2 = tx + g3 * 0.5f;
        const float ty1 = ty - g4 * 0.5f, ty2 = ty + g4 * 0.5f;
        const float tarea = (tx2 - tx1) * (ty2 - ty1);

        // ---- 4) IoU argmax over anchors (strict > => first-index on ties) ----
        int best = 0; float bestIoU = -1.0f;
        #pragma unroll
        for (int a = 0; a < 3; a++) {
            float c1 = __shfl(cellv, 5 + 4 * a + 0);
            float c2 = __shfl(cellv, 5 + 4 * a + 1);
            float c3 = __shfl(cellv, 5 + 4 * a + 2);
            float c4 = __shfl(cellv, 5 + 4 * a + 3);
            float ax  = (c1 + jf) * invG;
            float ay  = (c2 + if_) * invG;
            float ax1 = ax - c3 * 0.5f, ax2 = ax + c3 * 0.5f;
            float ay1 = ay - c4 * 0.5f, ay2 = ay + c4 * 0.5f;
            float iw = fminf(ax2, tx2) - fmaxf(ax1, tx1); iw = fmaxf(iw, 0.0f);
            float ih = fminf(ay2, ty2) - fmaxf(ay1, ty1); ih = fmaxf(ih, 0.0f);
            float inter = iw * ih;
            float uni   = (ax2 - ax1) * (ay2 - ay1) + tarea - inter;
            float iou   = inter / (uni + 1e-9f);
            if (iou > bestIoU) { bestIoU = iou; best = a; }
        }

        const float px = __shfl(cellv, 5 + 4 * best + 0);
        const float py = __shfl(cellv, 5 + 4 * best + 1);
        const float pw = __shfl(cellv, 5 + 4 * best + 2);
        const float ph = __shfl(cellv, 5 + 4 * best + 3);

        // ---- 5) prob_loss partials: sum over 3 channels of -log(1-p),
        //          plus best-channel correction -t*(log p - log(1-p)) ----
        float s = 0.0f;
        if (lane < GG_) {
            float l1p0 = __logf(1.0f - p0);
            float l1p1 = __logf(1.0f - p1);
            float l1p2 = __logf(1.0f - p2);
            s = -(l1p0 + l1p1 + l1p2);
            float pb   = (best == 0) ? p0 : ((best == 1) ? p1 : p2);
            float l1pb = (best == 0) ? l1p0 : ((best == 1) ? l1p1 : l1p2);
            s -= t * (__logf(pb) - l1pb);
        }
        acc += s * invN49;

        // ---- 6) coord (BCE sum) + size (log-diff L1 sum) + CE mean ----
        if (lane == 0) {
            float coord = -(g1 * __logf(px) + (1.0f - g1) * __logf(1.0f - px))
                          -(g2 * __logf(py) + (1.0f - g2) * __logf(1.0f - py));
            float size  = fabsf(__logf(pw) - __logf(g3))
                        + fabsf(__logf(ph) - __logf(g4));
            float x0 = cls_logits[2 * n], x1 = cls_logits[2 * n + 1];
            int   c  = cls_lbl[n] - 1;
            float mx  = fmaxf(x0, x1);
            float lse = mx + __logf(__expf(x0 - mx) + __expf(x1 - mx));
            float lp  = ((c == 0) ? x0 : x1) - lse;
            acc += coord + size - lp * invN;
        }
    }

    // ---- block reduction, one atomic per block ----
    #pragma unroll
    for (int off = 32; off; off >>= 1) acc += __shfl_xor(acc, off);
    __shared__ float wsum[4];
    if (lane == 0) wsum[threadIdx.x >> 6] = acc;
    __syncthreads();
    if (threadIdx.x == 0) {
        atomicAdd(out, wsum[0] + wsum[1] + wsum[2] + wsum[3]);
    }
}

extern "C" void kernel_launch(void* const* d_in, const int* in_sizes, int n_in,
                              void* d_out, int out_size, void* d_ws, size_t ws_size,
                              hipStream_t stream) {
    const float* bbox_p = (const float*)d_in[0];   // (N,15,7,7)
    const float* cls_p  = (const float*)d_in[1];   // (N,2)
    const float* bbox_g = (const float*)d_in[2];   // (N,5,7,7)
    const int*   cls_l  = (const int*)d_in[3];     // (N,)
    float* out = (float*)d_out;
    const int N = in_sizes[3];

    hipLaunchKernelGGL(zero_kernel, dim3(1), dim3(64), 0, stream, out);
    // 2048 blocks x 4 waves = 8192 waves, 8 samples/wave; 2048 atomics total.
    hipLaunchKernelGGL(loss_kernel, dim3(2048), dim3(256), 0, stream,
                       bbox_p, cls_p, bbox_g, cls_l, out, N);
}